// Round 9
// baseline (906.353 us; speedup 1.0000x reference)
//
#include <hip/hip_runtime.h>
#include <math.h>

#define NEGBIG (-1e30f)
#define GLB_PTR(x) ((const __attribute__((address_space(1))) void*)(x))
#define LDS_PTR(x) ((__attribute__((address_space(3))) void*)(x))

typedef __bf16 bf16x8 __attribute__((ext_vector_type(8)));
typedef float  f32x4  __attribute__((ext_vector_type(4)));

// Sizes: B=512, S=8, U=512, D=32, G=8, DIM_IN=4096, DAG=2048
// out layout: att[512*16384] | ga[512*2048] | w[512^3] | outputs[512*16384]
// No-max softmax: scores kernel stores p = exp(s) (masked -> 0) into the w
// region and accumulates L_g; stats cell (b,u) floats [0..7] = 1/(8 L_g).
// emit kernel: w = p * IL_g + PV accumulation; overwrites stats cells.

// ---------------- K1/K2: per-split fp32 GEMM (64x64 tile, Kstep 16) ----------------
__global__ __launch_bounds__(256) void gemm_split(
    const float* __restrict__ A, int lda, int Ksz,
    const float* __restrict__ Bw, int NS,
    const float* __restrict__ bias,
    float* __restrict__ C, int ldc)
{
  const int n0 = blockIdx.x * 64;
  const int b0 = blockIdx.y * 64;
  const int s  = n0 / NS;
  const float* Bp = Bw + (size_t)s * Ksz * NS;
  const int nloc0 = n0 - s * NS;
  const int acol0 = s * Ksz;

  __shared__ float As[16][64];
  __shared__ float Bs[16][64];

  const int t  = threadIdx.x;
  const int tb = t & 15, tn = t >> 4;
  float acc[4][4] = {};

  for (int k0 = 0; k0 < Ksz; k0 += 16) {
    {
      int r = t & 63, g = t >> 6;
      float4 v = *reinterpret_cast<const float4*>(
          A + (size_t)(b0 + r) * lda + acol0 + k0 + 4 * g);
      As[4*g+0][r] = v.x; As[4*g+1][r] = v.y; As[4*g+2][r] = v.z; As[4*g+3][r] = v.w;
    }
    {
      int kk = t >> 4, n4 = t & 15;
      float4 v = *reinterpret_cast<const float4*>(
          Bp + (size_t)(k0 + kk) * NS + nloc0 + 4 * n4);
      *reinterpret_cast<float4*>(&Bs[kk][4*n4]) = v;
    }
    __syncthreads();
#pragma unroll
    for (int k = 0; k < 16; ++k) {
      float4 a4 = *reinterpret_cast<const float4*>(&As[k][4*tb]);
      float4 b4 = *reinterpret_cast<const float4*>(&Bs[k][4*tn]);
      float av[4] = {a4.x, a4.y, a4.z, a4.w};
      float bv[4] = {b4.x, b4.y, b4.z, b4.w};
#pragma unroll
      for (int i = 0; i < 4; ++i)
#pragma unroll
        for (int j = 0; j < 4; ++j)
          acc[i][j] = fmaf(av[i], bv[j], acc[i][j]);
    }
    __syncthreads();
  }
#pragma unroll
  for (int i = 0; i < 4; ++i) {
    int row = b0 + 4*tb + i;
    int col = n0 + 4*tn;
    float4 o;
    o.x = acc[i][0] + bias[col + 0];
    o.y = acc[i][1] + bias[col + 1];
    o.z = acc[i][2] + bias[col + 2];
    o.w = acc[i][3] + bias[col + 3];
    *reinterpret_cast<float4*>(C + (size_t)row * ldc + col) = o;
  }
}

// ---------------- K3a (MFMA v2): p = exp(masked score) + group sums ----------------
// Block 16b x 16u; 16-m chunks. ma staged via global_load_lds into f4-slots
//   s = (m<<7) + (u<<3) + (d4 ^ (m&7))     (source-side swizzle; reads 2-way).
// Wave w owns u-locals 4w..4w+3; A-frags (att) split hi/lo bf16 in regs ONCE.
// Per chunk/u: B-frag = 2 swizzled LDS f4 reads + split; 3 MFMAs (hi*lo +
// lo*hi + hi*hi); C -> tr[(b*16+m)*17 + u].
// Emit role: thread (bl,ml) owns (b, m=16c+ml) for 16 u: coalesced rnd f4
// (issued before MFMA phase), p = exp(s*tmp) (masked -> 0), coalesced 64 B
// w-writes, Ls[16] in regs (g = ml&7 static). shfl_xor(8) merges the m/m+8
// partners; ml<8 lanes write IL = 1/(8L) to stats cell [g].
__global__ __launch_bounds__(256) void scores_mfma_v2(
    const float* __restrict__ att,   // [512][512][32]
    const float* __restrict__ ma,    // [512][512][32]
    const float* __restrict__ rnd,   // [512][512][512]
    const float* __restrict__ temp,  // [512]
    float* __restrict__ wout,        // [512][512][512] <- p values
    float* __restrict__ stats)       // outs region base
{
  __shared__ float MaL[2048 * 4];    // 32 KB: staged ma chunk (f4 slots)
  __shared__ float tr[256 * 17];     // 17 KB: C transpose
  const int b0 = blockIdx.x * 16;
  const int u0 = blockIdx.y * 16;
  const int t  = threadIdx.x;
  const int w  = t >> 6, l = t & 63;
  const int lm = l & 15, kb = l >> 4;      // MFMA lane decode (row/col, k-block)
  const int bl = t >> 4, ml = t & 15;      // emit decode
  const int gb = b0 + bl;

  // temperatures (emit role)
  float tvf[16];
#pragma unroll
  for (int q = 0; q < 4; ++q) {
    float4 tq = *reinterpret_cast<const float4*>(temp + u0 + 4 * q);
    tvf[4*q+0] = tq.x; tvf[4*q+1] = tq.y; tvf[4*q+2] = tq.z; tvf[4*q+3] = tq.w;
  }

  // A-fragments for this wave's 4 u's, split hi/lo bf16 (loaded once)
  bf16x8 Ahi[4], Alo[4];
#pragma unroll
  for (int q = 0; q < 4; ++q) {
    const float* ap = att + (size_t)(b0 + lm) * 16384
                    + (size_t)(u0 + 4 * w + q) * 32 + kb * 8;
    float4 a0 = *reinterpret_cast<const float4*>(ap);
    float4 a1 = *reinterpret_cast<const float4*>(ap + 4);
    float af[8] = {a0.x, a0.y, a0.z, a0.w, a1.x, a1.y, a1.z, a1.w};
#pragma unroll
    for (int j = 0; j < 8; ++j) {
      __bf16 h = (__bf16)af[j];
      Ahi[q][j] = h;
      Alo[q][j] = (__bf16)(af[j] - (float)h);
    }
  }

  // staging source offsets: slot s = k*256 + t holds ma(m=s>>7, u=(s>>3)&15,
  // d4 = (s&7) ^ (m&7)) of the current chunk
  int off[8];
#pragma unroll
  for (int k = 0; k < 8; ++k) {
    int s = k * 256 + t;
    int mm = s >> 7, uu = (s >> 3) & 15, d4s = s & 7;
    off[k] = mm * 16384 + (u0 + uu) * 32 + ((d4s ^ (mm & 7)) << 2);
  }

  float Ls[16];
#pragma unroll
  for (int u = 0; u < 16; ++u) Ls[u] = 0.f;

  const float* rb = rnd  + (size_t)gb * 262144 + u0;
  float*       wb = wout + (size_t)gb * 262144 + u0;

  // prologue: stage chunk 0
#pragma unroll
  for (int k = 0; k < 8; ++k)
    __builtin_amdgcn_global_load_lds(GLB_PTR(ma + (size_t)off[k]),
                                     LDS_PTR(&MaL[(k * 256 + w * 64) * 4]), 16, 0, 0);

#pragma unroll 1
  for (int c = 0; c < 32; ++c) {
    const int m0 = c * 16;
    __syncthreads();                 // MaL[c] drained; tr free (prev emit done)

    // rnd loads for this chunk (consumed in emit; fly across MFMA phase)
    float4 rv[4];
#pragma unroll
    for (int q = 0; q < 4; ++q)
      rv[q] = *reinterpret_cast<const float4*>(rb + (size_t)(m0 + ml) * 512 + 4 * q);

    // ---- MFMA role: 4 u's ----
#pragma unroll
    for (int q = 0; q < 4; ++q) {
      const int uq = 4 * w + q;
      const int s0 = (lm << 7) + (uq << 3) + ((2 * kb)     ^ (lm & 7));
      const int s1 = (lm << 7) + (uq << 3) + ((2 * kb + 1) ^ (lm & 7));
      float4 g0 = *reinterpret_cast<const float4*>(&MaL[s0 * 4]);
      float4 g1 = *reinterpret_cast<const float4*>(&MaL[s1 * 4]);
      float bf[8] = {g0.x, g0.y, g0.z, g0.w, g1.x, g1.y, g1.z, g1.w};
      bf16x8 Bhi, Blo;
#pragma unroll
      for (int j = 0; j < 8; ++j) {
        __bf16 h = (__bf16)bf[j];
        Bhi[j] = h;
        Blo[j] = (__bf16)(bf[j] - (float)h);
      }
      f32x4 acc = {0.f, 0.f, 0.f, 0.f};
      acc = __builtin_amdgcn_mfma_f32_16x16x32_bf16(Ahi[q], Blo, acc, 0, 0, 0);
      acc = __builtin_amdgcn_mfma_f32_16x16x32_bf16(Alo[q], Bhi, acc, 0, 0, 0);
      acc = __builtin_amdgcn_mfma_f32_16x16x32_bf16(Ahi[q], Bhi, acc, 0, 0, 0);
      // C: row(b) = kb*4+i, col(m) = lm
#pragma unroll
      for (int i = 0; i < 4; ++i)
        tr[((kb * 4 + i) * 16 + lm) * 17 + uq] = acc[i];
    }
    __syncthreads();                 // tr ready; MaL free

    // issue next chunk's staging now: overlaps the emit phase below
    if (c < 31) {
#pragma unroll
      for (int k = 0; k < 8; ++k)
        __builtin_amdgcn_global_load_lds(
            GLB_PTR(ma + (size_t)off[k] + (size_t)(m0 + 16) * 16384),
            LDS_PTR(&MaL[(k * 256 + w * 64) * 4]), 16, 0, 0);
    }

    // ---- emit role ----
    const int gm = m0 + ml;
    const bool dg = (gm == gb);
    const float* trow = &tr[(bl * 16 + ml) * 17];
    float* wp = wb + (size_t)gm * 512;
#pragma unroll
    for (int q = 0; q < 4; ++q) {
      float rr[4] = {rv[q].x, rv[q].y, rv[q].z, rv[q].w};
      float sv[4];
#pragma unroll
      for (int e = 0; e < 4; ++e) {
        const int u = 4 * q + e;
        float p;
        if ((rr[e] < 0.1f) | dg) p = 0.f;
        else                     p = __expf(trow[u] * tvf[u]);
        sv[e] = p;
        Ls[u] += p;
      }
      *reinterpret_cast<float4*>(wp + 4 * q) =
          make_float4(sv[0], sv[1], sv[2], sv[3]);
    }
  }

  // ---- merge (ml, ml^8) partners; write IL ----
  float tot[16];
#pragma unroll
  for (int u = 0; u < 16; ++u)
    tot[u] = Ls[u] + __shfl_xor(Ls[u], 8, 64);
  if (ml < 8) {
#pragma unroll
    for (int u = 0; u < 16; ++u)
      stats[((size_t)gb * 512 + u0 + u) * 32 + ml] = 1.0f / (8.0f * tot[u]);
  }
}

// ---------------- K3b v3: w = p*IL + outputs, 16b x 16u blocks ----------------
__global__ __launch_bounds__(256) void emit_outputs_v3(
    const float* __restrict__ mo,    // [512][512][32]
    float* __restrict__ w,           // in: p values, out: final w
    float* __restrict__ outs)        // in: stats cells (IL), out: outputs
{
  __shared__ float MoL[8 * 16 * 32];
  __shared__ float E[8 * 16 * 17];
  const int u0 = blockIdx.x * 16;
  const int b0 = blockIdx.y * 16;
  const int t  = threadIdx.x;
  const int ab = t >> 4, am = (t >> 1) & 7, uh = t & 1;
  const int pu = t >> 4, bq = (t >> 2) & 3, dh = t & 3;

  float Sreg[8];
  {
    const float* cb = outs + ((size_t)(b0 + ab) * 512 + u0 + uh * 8) * 32;
#pragma unroll
    for (int j = 0; j < 8; ++j) Sreg[j] = cb[j * 32 + am];
  }

  float4 acc[4][2];
#pragma unroll
  for (int i = 0; i < 4; ++i) {
    acc[i][0] = make_float4(0.f, 0.f, 0.f, 0.f);
    acc[i][1] = make_float4(0.f, 0.f, 0.f, 0.f);
  }

  float* wbase = w + (size_t)(b0 + ab) * 262144 + u0 + uh * 8;   // + m*512

  const float* msrc0;  const float* msrc1;  const float* msrc2;  const float* msrc3;
  int loff0, loff1, loff2, loff3;
  {
    int P, mm, uu, dq;
    P = t;          mm = P >> 7; uu = (P >> 3) & 15; dq = P & 7;
    msrc0 = mo + (size_t)mm * 16384 + (size_t)(u0 + uu) * 32 + (dq ^ (uu & 7)) * 4;
    loff0 = P * 4;
    P = 256 + t;    mm = P >> 7; uu = (P >> 3) & 15; dq = P & 7;
    msrc1 = mo + (size_t)mm * 16384 + (size_t)(u0 + uu) * 32 + (dq ^ (uu & 7)) * 4;
    loff1 = P * 4;
    P = 512 + t;    mm = P >> 7; uu = (P >> 3) & 15; dq = P & 7;
    msrc2 = mo + (size_t)mm * 16384 + (size_t)(u0 + uu) * 32 + (dq ^ (uu & 7)) * 4;
    loff2 = P * 4;
    P = 768 + t;    mm = P >> 7; uu = (P >> 3) & 15; dq = P & 7;
    msrc3 = mo + (size_t)mm * 16384 + (size_t)(u0 + uu) * 32 + (dq ^ (uu & 7)) * 4;
    loff3 = P * 4;
  }

  float4 wpre0, wpre1, smo0, smo1, smo2, smo3;
  {
    const float* wp = wbase + (size_t)am * 512;
    wpre0 = *reinterpret_cast<const float4*>(wp);
    wpre1 = *reinterpret_cast<const float4*>(wp + 4);
    smo0 = *reinterpret_cast<const float4*>(msrc0);
    smo1 = *reinterpret_cast<const float4*>(msrc1);
    smo2 = *reinterpret_cast<const float4*>(msrc2);
    smo3 = *reinterpret_cast<const float4*>(msrc3);
  }

#pragma unroll 1
  for (int c = 0; c < 64; ++c) {
    const int mc = c * 8;
    if (c) __syncthreads();            // phase B of c-1 done with E/MoL

    // ---- phase A: v = p*IL, write w + E; ds_write staged mo ----
    {
      float* wp = wbase + (size_t)(mc + am) * 512;
      float s0[4] = {wpre0.x, wpre0.y, wpre0.z, wpre0.w};
      float s1[4] = {wpre1.x, wpre1.y, wpre1.z, wpre1.w};
#pragma unroll
      for (int e2 = 0; e2 < 4; ++e2) {
        float v = s0[e2] * Sreg[e2];
        s0[e2] = v;
        E[(am * 16 + uh * 8 + e2) * 17 + ab] = v;
      }
#pragma unroll
      for (int e2 = 0; e2 < 4; ++e2) {
        float v = s1[e2] * Sreg[4 + e2];
        s1[e2] = v;
        E[(am * 16 + uh * 8 + 4 + e2) * 17 + ab] = v;
      }
      *reinterpret_cast<float4*>(wp)     = make_float4(s0[0], s0[1], s0[2], s0[3]);
      *reinterpret_cast<float4*>(wp + 4) = make_float4(s1[0], s1[1], s1[2], s1[3]);
    }
    *reinterpret_cast<float4*>(&MoL[loff0]) = smo0;
    *reinterpret_cast<float4*>(&MoL[loff1]) = smo1;
    *reinterpret_cast<float4*>(&MoL[loff2]) = smo2;
    *reinterpret_cast<float4*>(&MoL[loff3]) = smo3;
    __syncthreads();                   // E + MoL ready

    // ---- issue prefetch for chunk c+1 ----
    if (c < 63) {
      const float* wp = wbase + (size_t)(mc + 8 + am) * 512;
      wpre0 = *reinterpret_cast<const float4*>(wp);
      wpre1 = *reinterpret_cast<const float4*>(wp + 4);
      const size_t moff = (size_t)(mc + 8) * 16384;
      smo0 = *reinterpret_cast<const float4*>(msrc0 + moff);
      smo1 = *reinterpret_cast<const float4*>(msrc1 + moff);
      smo2 = *reinterpret_cast<const float4*>(msrc2 + moff);
      smo3 = *reinterpret_cast<const float4*>(msrc3 + moff);
    }

    // ---- phase B: acc[4b][8d] += E[m][pu][4b] * Mo[m][pu][8d] ----
#pragma unroll
    for (int m = 0; m < 8; ++m) {
      float4 ef = *reinterpret_cast<const float4*>(&E[(m * 16 + pu) * 17 + 4 * bq]);
      float4 v0 = *reinterpret_cast<const float4*>(
          &MoL[(m * 16 + pu) * 32 + (((2 * dh) ^ (pu & 7)) * 4)]);
      float4 v1 = *reinterpret_cast<const float4*>(
          &MoL[(m * 16 + pu) * 32 + (((2 * dh + 1) ^ (pu & 7)) * 4)]);
      float es[4] = {ef.x, ef.y, ef.z, ef.w};
#pragma unroll
      for (int i = 0; i < 4; ++i) {
        acc[i][0].x = fmaf(es[i], v0.x, acc[i][0].x);
        acc[i][0].y = fmaf(es[i], v0.y, acc[i][0].y);
        acc[i][0].z = fmaf(es[i], v0.z, acc[i][0].z);
        acc[i][0].w = fmaf(es[i], v0.w, acc[i][0].w);
        acc[i][1].x = fmaf(es[i], v1.x, acc[i][1].x);
        acc[i][1].y = fmaf(es[i], v1.y, acc[i][1].y);
        acc[i][1].z = fmaf(es[i], v1.z, acc[i][1].z);
        acc[i][1].w = fmaf(es[i], v1.w, acc[i][1].w);
      }
    }
  }

  // epilogue: overwrite stats cells with final outputs
#pragma unroll
  for (int i = 0; i < 4; ++i) {
    float* dst = outs + ((size_t)(b0 + 4 * bq + i) * 512 + u0 + pu) * 32 + 8 * dh;
    *reinterpret_cast<float4*>(dst)     = acc[i][0];
    *reinterpret_cast<float4*>(dst + 4) = acc[i][1];
  }
}

extern "C" void kernel_launch(void* const* d_in, const int* in_sizes, int n_in,
                              void* d_out, int out_size, void* d_ws, size_t ws_size,
                              hipStream_t stream) {
  const float* x    = (const float*)d_in[0];   // [512][4096]
  const float* ma   = (const float*)d_in[1];   // [512][512][32]
  const float* mo   = (const float*)d_in[2];   // [512][512][32]
  const float* rnd  = (const float*)d_in[3];   // [512][512][512]
  const float* w1   = (const float*)d_in[4];   // [8][512][256]
  const float* b1   = (const float*)d_in[5];   // [8][256]
  const float* w2   = (const float*)d_in[6];   // [8][256][2048]
  const float* b2   = (const float*)d_in[7];   // [8][2048]
  const float* temp = (const float*)d_in[8];   // [512]

  float* out  = (float*)d_out;
  float* att  = out;                  // 8388608
  float* ga   = out + 8388608;        // 1048576
  float* wbuf = out + 9437184;        // 134217728
  float* outs = out + 143654912;      // 8388608

  gemm_split<<<dim3(32, 8), 256, 0, stream>>>(x, 4096, 512, w1, 256, b1, ga, 2048);
  gemm_split<<<dim3(256, 8), 256, 0, stream>>>(ga, 2048, 256, w2, 2048, b2, att, 16384);
  scores_mfma_v2<<<dim3(32, 32), 256, 0, stream>>>(att, ma, rnd, temp, wbuf, outs);
  emit_outputs_v3<<<dim3(32, 32), 256, 0, stream>>>(mo, wbuf, outs);
}